// Round 13
// baseline (269.417 us; speedup 1.0000x reference)
//
#include <hip/hip_runtime.h>
#include <hip/hip_bf16.h>

// ---------------- problem constants ----------------
#define DIMD 384
#define HEADS 6
#define DH 64
#define LEVELS 3
#define POINTS 4
#define FFN 1024
#define BB 4
#define NQ 4096
#define NV 21504
#define MQ (BB*NQ)   // 16384
#define MV (BB*NV)   // 86016
#define EPSF 1e-6f

typedef __hip_bfloat16 bf16;
typedef __attribute__((ext_vector_type(8))) short bf16x8;
typedef __attribute__((ext_vector_type(4))) float f32x4;

__device__ __forceinline__ float wave_sum(float v){
  #pragma unroll
  for(int o=32;o;o>>=1) v += __shfl_xor(v,o);
  return v;
}

__device__ __forceinline__ bf16x8 cvt8(f32x4 a, f32x4 b){
  bf16x8 r;
  r[0]=__builtin_bit_cast(short,__float2bfloat16(a[0]));
  r[1]=__builtin_bit_cast(short,__float2bfloat16(a[1]));
  r[2]=__builtin_bit_cast(short,__float2bfloat16(a[2]));
  r[3]=__builtin_bit_cast(short,__float2bfloat16(a[3]));
  r[4]=__builtin_bit_cast(short,__float2bfloat16(b[0]));
  r[5]=__builtin_bit_cast(short,__float2bfloat16(b[1]));
  r[6]=__builtin_bit_cast(short,__float2bfloat16(b[2]));
  r[7]=__builtin_bit_cast(short,__float2bfloat16(b[3]));
  return r;
}

// ---------------- fused: weight prep + u1/c0 + LN(query) ----------------
// blocks [0,NPREP): weights (wvg = Wv*diag(fn_g) folded).
// blocks [NPREP, NPREP+NVPREP): u1[n]=<Wv[n,:],fn_g>, c0[n]=<Wv[n,:],fn_b>+b_v[n].
// rest: LN(query) -> qn bf16 (16 rows/block, float4/short4 vectorized).
#define NPREP 4609
#define NVPREP 96
__global__ __launch_bounds__(256) void pre_k(
  const float* __restrict__ Wv, const float* __restrict__ Wo,
  const float* __restrict__ W1, const float* __restrict__ W2,
  const float* __restrict__ Woff, const float* __restrict__ Waw,
  const float* __restrict__ boff, const float* __restrict__ baw,
  const float* __restrict__ fng, const float* __restrict__ fnb,
  const float* __restrict__ bv,
  bf16* __restrict__ wvg, bf16* __restrict__ wo, bf16* __restrict__ w1,
  bf16* __restrict__ w2, bf16* __restrict__ wcat, float* __restrict__ bcat,
  float* __restrict__ u1, float* __restrict__ c0,
  const float* __restrict__ query, const float* __restrict__ qg,
  const float* __restrict__ qb, bf16* __restrict__ qn)
{
  const int blk = blockIdx.x;
  if(blk < NPREP){
    int i = blk*256 + threadIdx.x;
    if(i < 147456){ wvg[i] = __float2bfloat16(Wv[i] * fng[i % 384]); return; }
    i -= 147456;
    if(i < 147456){ wo[i] = __float2bfloat16(Wo[i]); return; }
    i -= 147456;
    if(i < 393216){ w1[i] = __float2bfloat16(W1[i]); return; }
    i -= 393216;
    if(i < 393216){ w2[i] = __float2bfloat16(W2[i]); return; }
    i -= 393216;
    if(i < 98304){
      int r = i/384, c = i - r*384;
      float v = r<144 ? Woff[r*384+c] : (r<216 ? Waw[(r-144)*384+c] : 0.f);
      wcat[i] = __float2bfloat16(v); return;
    }
    i -= 98304;
    if(i < 256){ bcat[i] = i<144 ? boff[i] : (i<216 ? baw[i-144] : 0.f); }
    return;
  }
  if(blk < NPREP + NVPREP){
    const int n = (blk - NPREP)*4 + (threadIdx.x>>6);
    const int lane = threadIdx.x & 63;
    float s1=0.f, s0=0.f;
    #pragma unroll
    for(int i=0;i<6;i++){
      const int k = lane + i*64;
      const float w = Wv[(size_t)n*DIMD + k];
      s1 += w*fng[k]; s0 += w*fnb[k];
    }
    s1 = wave_sum(s1); s0 = wave_sum(s0);
    if(lane==0){ u1[n] = s1; c0[n] = s0 + bv[n]; }
    return;
  }
  const int lblk = blk - NPREP - NVPREP;
  const int row = lblk*16 + (threadIdx.x>>4);
  const int li  = threadIdx.x & 15;
  float4 va[6];
  float s=0.f, s2=0.f;
  const float* xr = query + (size_t)row*DIMD + li*4;
  #pragma unroll
  for(int j=0;j<6;j++){
    va[j] = *(const float4*)(xr + j*64);
    s  += va[j].x + va[j].y + va[j].z + va[j].w;
    s2 += va[j].x*va[j].x + va[j].y*va[j].y + va[j].z*va[j].z + va[j].w*va[j].w;
  }
  #pragma unroll
  for(int off=1; off<16; off<<=1){ s += __shfl_xor(s,off); s2 += __shfl_xor(s2,off); }
  const float m = s*(1.f/DIMD);
  const float r = rsqrtf(s2*(1.f/DIMD) - m*m + EPSF);
  #pragma unroll
  for(int j=0;j<6;j++){
    const int col = li*4 + j*64;
    const float4 g4 = *(const float4*)(qg + col);
    const float4 b4 = *(const float4*)(qb + col);
    short4 o4;
    o4.x = __builtin_bit_cast(short, __float2bfloat16((va[j].x-m)*r*g4.x + b4.x));
    o4.y = __builtin_bit_cast(short, __float2bfloat16((va[j].y-m)*r*g4.y + b4.y));
    o4.z = __builtin_bit_cast(short, __float2bfloat16((va[j].z-m)*r*g4.z + b4.z));
    o4.w = __builtin_bit_cast(short, __float2bfloat16((va[j].w-m)*r*g4.w + b4.w));
    *(short4*)((short*)qn + (size_t)row*DIMD + col) = o4;
  }
}

// ---------------- merged GEMM: fused-LN v-proj (blocks < NVB) + offaw (rest) ----------------
// v-proj: A = RAW fp32 feat staged via global_load_lds; fragments cvt fp32->bf16;
// row stats read back from the staged LDS tile; epilogue v = rs*acc - m*rs*u1 + c0.
// offaw: unchanged bf16 path (A2=qn, B2=wcat 256 rows, out fp32 ldc 216).
#define NVB (MV/64)   // 1344
__global__ __launch_bounds__(512,2) void gemm2_k(
    const float* __restrict__ feat, const bf16* __restrict__ wvg,
    const float* __restrict__ u1, const float* __restrict__ c0,
    bf16* __restrict__ out1,
    const bf16* __restrict__ A2, const bf16* __restrict__ B2,
    const float* __restrict__ bias2, float* __restrict__ out2)
{
  __shared__ __align__(16) float AsF[64*64];     // 16 KB (v: fp32 tile; offaw: bf16 view)
  __shared__ __align__(16) short Bs[384*64];     // 48 KB
  __shared__ float st[64*2];
  short* As = (short*)AsF;
  const int tid = threadIdx.x;
  const int wid = tid>>6, lane = tid&63;
  const int lr8 = lane>>3, lc8 = (lane&7)*8;
  const int cg = lane>>4;
  const bool vbr = blockIdx.x < NVB;

  if(vbr){
    const int m0 = blockIdx.x*64;
    const int srow = tid>>3, scol = (tid&7)*8;   // stats assignment
    f32x4 acc[4][3] = {};
    float s=0.f, s2=0.f;
    for(int k0=0; k0<DIMD; k0+=64){
      // stage A fp32 [64][64]: 2 instrs/wave, 1 KB each (4 rows)
      #pragma unroll
      for(int u=0;u<2;u++){
        const int t = wid*2 + u;                 // 0..15
        const float* srcA = feat + (size_t)(m0 + t*4 + (lane>>4))*DIMD + k0 + (lane&15)*4;
        __builtin_amdgcn_global_load_lds((const __attribute__((address_space(1))) void*)srcA,
            (__attribute__((address_space(3))) void*)(AsF + t*256), 16, 0, 0);
      }
      // stage B bf16 [384][64]
      #pragma unroll
      for(int u=0;u<6;u++){
        const int t = wid*6 + u;
        const bf16* srcB = wvg + (size_t)(t*8 + lr8)*DIMD + k0 + lc8;
        __builtin_amdgcn_global_load_lds((const __attribute__((address_space(1))) void*)srcB,
            (__attribute__((address_space(3))) void*)(Bs + t*512), 16, 0, 0);
      }
      asm volatile("s_waitcnt vmcnt(0)" ::: "memory");
      __syncthreads();
      // row-stats partial from the staged fp32 tile (8 threads/row, 8 cols each)
      {
        f32x4 p0 = *(const f32x4*)(AsF + srow*64 + scol);
        f32x4 p1 = *(const f32x4*)(AsF + srow*64 + scol + 4);
        #pragma unroll
        for(int e=0;e<4;e++){
          s += p0[e] + p1[e];
          s2 += p0[e]*p0[e] + p1[e]*p1[e];
        }
      }
      #pragma unroll
      for(int ks=0;ks<2;ks++){
        const int cbase = ks*32 + cg*8;
        bf16x8 af[4], bfr[3];
        #pragma unroll
        for(int i=0;i<4;i++){
          const int ar = i*16 + (lane&15);
          f32x4 q0 = *(const f32x4*)(AsF + ar*64 + cbase);
          f32x4 q1 = *(const f32x4*)(AsF + ar*64 + cbase + 4);
          af[i] = cvt8(q0, q1);
        }
        #pragma unroll
        for(int j=0;j<3;j++)
          bfr[j] = *(const bf16x8*)(Bs + (wid*48 + j*16 + (lane&15))*64 + cbase);
        #pragma unroll
        for(int i=0;i<4;i++)
          #pragma unroll
          for(int j=0;j<3;j++)
            acc[i][j] = __builtin_amdgcn_mfma_f32_16x16x32_bf16(af[i], bfr[j], acc[i][j], 0,0,0);
      }
      __syncthreads();
    }
    // finalize row stats: reduce over the 8 threads sharing a row
    s  += __shfl_xor(s,1);  s  += __shfl_xor(s,2);  s  += __shfl_xor(s,4);
    s2 += __shfl_xor(s2,1); s2 += __shfl_xor(s2,2); s2 += __shfl_xor(s2,4);
    if((tid&7)==0){
      const float m  = s*(1.f/DIMD);
      const float rs = rsqrtf(s2*(1.f/DIMD) - m*m + EPSF);
      st[2*srow] = rs; st[2*srow+1] = m*rs;
    }
    __syncthreads();
    // epilogue: v = rs*acc - m*rs*u1 + c0
    #pragma unroll
    for(int i=0;i<4;i++){
      #pragma unroll
      for(int j=0;j<3;j++){
        const int col = wid*48 + j*16 + (lane&15);
        const float u1c = u1[col], c0c = c0[col];
        #pragma unroll
        for(int rr=0;rr<4;rr++){
          const int r = i*16 + cg*4 + rr;
          const float v = st[2*r]*acc[i][j][rr] - st[2*r+1]*u1c + c0c;
          out1[(size_t)(m0+r)*DIMD + col] = __float2bfloat16(v);
        }
      }
    }
  } else {
    const int m0 = (blockIdx.x - NVB)*64;
    f32x4 acc[4][2] = {};
    for(int k0=0; k0<DIMD; k0+=64){
      {
        const bf16* srcA = A2 + (size_t)(m0 + wid*8 + lr8)*DIMD + k0 + lc8;
        __builtin_amdgcn_global_load_lds((const __attribute__((address_space(1))) void*)srcA,
            (__attribute__((address_space(3))) void*)(As + wid*512), 16, 0, 0);
      }
      #pragma unroll
      for(int u=0;u<4;u++){
        const int t = wid*4 + u;
        const bf16* srcB = B2 + (size_t)(t*8 + lr8)*DIMD + k0 + lc8;
        __builtin_amdgcn_global_load_lds((const __attribute__((address_space(1))) void*)srcB,
            (__attribute__((address_space(3))) void*)(Bs + t*512), 16, 0, 0);
      }
      asm volatile("s_waitcnt vmcnt(0)" ::: "memory");
      __syncthreads();
      #pragma unroll
      for(int ks=0;ks<2;ks++){
        const int cbase = ks*32 + cg*8;
        bf16x8 af[4], bfr[2];
        #pragma unroll
        for(int i=0;i<4;i++)
          af[i] = *(const bf16x8*)(As + (i*16 + (lane&15))*64 + cbase);
        #pragma unroll
        for(int j=0;j<2;j++)
          bfr[j] = *(const bf16x8*)(Bs + (wid*32 + j*16 + (lane&15))*64 + cbase);
        #pragma unroll
        for(int i=0;i<4;i++)
          #pragma unroll
          for(int j=0;j<2;j++)
            acc[i][j] = __builtin_amdgcn_mfma_f32_16x16x32_bf16(af[i], bfr[j], acc[i][j], 0,0,0);
      }
      __syncthreads();
    }
    #pragma unroll
    for(int i=0;i<4;i++){
      const int r0 = m0 + i*16 + cg*4;
      #pragma unroll
      for(int j=0;j<2;j++){
        const int col = wid*32 + j*16 + (lane&15);
        if(col >= 216) continue;
        const float bv = bias2[col];
        #pragma unroll
        for(int rr=0;rr<4;rr++)
          out2[(size_t)(r0+rr)*216 + col] = acc[i][j][rr] + bv;
      }
    }
  }
}

// ---------------- TM-row x 384-col GEMM with fused row-LN epilogue ----------------
template<int KK,int MODE,int TM>
__global__ __launch_bounds__(512,2) void gl_k(
    const bf16* __restrict__ A, const bf16* __restrict__ Bw,
    const float* __restrict__ bias, const bf16* __restrict__ res,
    const float* __restrict__ g, const float* __restrict__ b,
    const float* __restrict__ gam, const float* __restrict__ qsrc,
    void* __restrict__ out)
{
  constexpr int MI = TM/16;
  __shared__ __align__(16) short As[64*64];
  __shared__ __align__(16) short Bs[384*64];
  __shared__ float wst[8*64*2];
  __shared__ float st[64*2];
  const int tid = threadIdx.x;
  const int wid = tid>>6, lane = tid&63;
  const int m0 = blockIdx.x*TM;
  const int lr8 = lane>>3, lc8 = (lane&7)*8;
  const int cg = lane>>4;
  f32x4 acc[MI][3] = {};

  for(int k0=0; k0<KK; k0+=64){
    if(wid < TM/8){
      const bf16* srcA = A + (size_t)(m0 + wid*8 + lr8)*KK + k0 + lc8;
      __builtin_amdgcn_global_load_lds((const __attribute__((address_space(1))) void*)srcA,
          (__attribute__((address_space(3))) void*)(As + wid*512), 16, 0, 0);
    }
    #pragma unroll
    for(int u=0;u<6;u++){
      const int t = wid*6 + u;
      const bf16* srcB = Bw + (size_t)(t*8 + lr8)*KK + k0 + lc8;
      __builtin_amdgcn_global_load_lds((const __attribute__((address_space(1))) void*)srcB,
          (__attribute__((address_space(3))) void*)(Bs + t*512), 16, 0, 0);
    }
    asm volatile("s_waitcnt vmcnt(0)" ::: "memory");
    __syncthreads();
    #pragma unroll
    for(int ks=0;ks<2;ks++){
      const int cbase = ks*32 + cg*8;
      bf16x8 af[MI], bfr[3];
      #pragma unroll
      for(int i=0;i<MI;i++)
        af[i] = *(const bf16x8*)(As + (i*16 + (lane&15))*64 + cbase);
      #pragma unroll
      for(int j=0;j<3;j++)
        bfr[j] = *(const bf16x8*)(Bs + (wid*48 + j*16 + (lane&15))*64 + cbase);
      #pragma unroll
      for(int i=0;i<MI;i++)
        #pragma unroll
        for(int j=0;j<3;j++)
          acc[i][j] = __builtin_amdgcn_mfma_f32_16x16x32_bf16(af[i], bfr[j], acc[i][j], 0,0,0);
    }
    __syncthreads();
  }

  float sA[MI][4], sB[MI][4];
  #pragma unroll
  for(int i=0;i<MI;i++)
    #pragma unroll
    for(int rr=0;rr<4;rr++){ sA[i][rr]=0.f; sB[i][rr]=0.f; }
  #pragma unroll
  for(int i=0;i<MI;i++){
    #pragma unroll
    for(int j=0;j<3;j++){
      const int col = wid*48 + j*16 + (lane&15);
      const float bv = bias[col];
      #pragma unroll
      for(int rr=0;rr<4;rr++){
        const int rowg = m0 + i*16 + cg*4 + rr;
        float v = acc[i][j][rr] + bv
                + __bfloat162float(res[(size_t)rowg*DIMD + col]);
        acc[i][j][rr] = v;
        sA[i][rr] += v; sB[i][rr] += v*v;
      }
    }
  }
  #pragma unroll
  for(int off=1; off<16; off<<=1){
    #pragma unroll
    for(int i=0;i<MI;i++)
      #pragma unroll
      for(int rr=0;rr<4;rr++){
        sA[i][rr] += __shfl_xor(sA[i][rr], off);
        sB[i][rr] += __shfl_xor(sB[i][rr], off);
      }
  }
  if((lane&15)==0){
    #pragma unroll
    for(int i=0;i<MI;i++)
      #pragma unroll
      for(int rr=0;rr<4;rr++){
        const int row = i*16 + cg*4 + rr;
        wst[(wid*TM + row)*2 + 0] = sA[i][rr];
        wst[(wid*TM + row)*2 + 1] = sB[i][rr];
      }
  }
  __syncthreads();
  if(tid < TM){
    float ms=0.f, m2=0.f;
    #pragma unroll
    for(int w=0;w<8;w++){ ms += wst[(w*TM+tid)*2]; m2 += wst[(w*TM+tid)*2+1]; }
    const float m  = ms*(1.f/DIMD);
    const float rs = rsqrtf(m2*(1.f/DIMD) - m*m + EPSF);
    st[tid*2] = m; st[tid*2+1] = rs;
  }
  __syncthreads();
  #pragma unroll
  for(int i=0;i<MI;i++){
    #pragma unroll
    for(int j=0;j<3;j++){
      const int col = wid*48 + j*16 + (lane&15);
      const float gc = g[col], bc = b[col];
      #pragma unroll
      for(int rr=0;rr<4;rr++){
        const int row = i*16 + cg*4 + rr;
        const int rowg = m0 + row;
        const float t = (acc[i][j][rr] - st[row*2])*st[row*2+1]*gc + bc;
        if constexpr(MODE == 1){
          ((bf16*)out)[(size_t)rowg*DIMD + col] = __float2bfloat16(t);
        } else {
          ((float*)out)[(size_t)rowg*DIMD + col] =
              qsrc[(size_t)rowg*DIMD + col] + gam[col]*t;
        }
      }
    }
  }
}

// ---------------- bf16 MFMA GEMM (128x128 tile): C = epi(A @ W^T + bias) ----------------
template<int GELU_,int STBF>
__global__ __launch_bounds__(256) void mgemm_k(
    const bf16* __restrict__ A, const bf16* __restrict__ Bw,
    const float* __restrict__ bias, void* __restrict__ Cv,
    int M, int K, int Nreal, int ldc)
{
  __shared__ __align__(16) short As[128*64];
  __shared__ __align__(16) short Bs[128*64];
  const int tid  = threadIdx.x;
  const int wid  = tid>>6, lane = tid&63;
  const int wr   = wid>>1, wc = wid&1;
  const int m0   = blockIdx.y*128, n0 = blockIdx.x*128;
  f32x4 acc[4][4] = {};

  const int sr = (lane>>3);
  const int sc = (lane&7)*8;

  for(int k0=0; k0<K; k0+=64){
    #pragma unroll
    for(int u=0;u<4;u++){
      const int t = wid*4 + u;
      const int r = t*8 + sr;
      const bf16* srcA = A  + (size_t)(m0+r)*K + k0 + sc;
      const bf16* srcB = Bw + (size_t)(n0+r)*K + k0 + sc;
      __builtin_amdgcn_global_load_lds((const __attribute__((address_space(1))) void*)srcA,
          (__attribute__((address_space(3))) void*)(As + t*512), 16, 0, 0);
      __builtin_amdgcn_global_load_lds((const __attribute__((address_space(1))) void*)srcB,
          (__attribute__((address_space(3))) void*)(Bs + t*512), 16, 0, 0);
    }
    asm volatile("s_waitcnt vmcnt(0)" ::: "memory");
    __syncthreads();
    #pragma unroll
    for(int ks=0;ks<2;ks++){
      bf16x8 af[4], bfr[4];
      #pragma unroll
      for(int i=0;i<4;i++){
        const int ar = wr*64 + i*16 + (lane&15);
        af[i]  = *(const bf16x8*)(As + ar*64 + ks*32 + (lane>>4)*8);
        const int br = wc*64 + i*16 + (lane&15);
        bfr[i] = *(const bf16x8*)(Bs + br*64 + ks*32 + (lane>>4)*8);
      }
      #pragma unroll
      for(int i=0;i<4;i++)
        #pragma unroll
        for(int j=0;j<4;j++)
          acc[i][j] = __builtin_amdgcn_mfma_f32_16x16x32_bf16(af[i], bfr[j], acc[i][j], 0,0,0);
    }
    __syncthreads();
  }
  #pragma unroll
  for(int i=0;i<4;i++){
    const int rbase = m0 + wr*64 + i*16 + (lane>>4)*4;
    #pragma unroll
    for(int j=0;j<4;j++){
      const int col = n0 + wc*64 + j*16 + (lane&15);
      if(col >= Nreal) continue;
      const float bv = bias[col];
      #pragma unroll
      for(int rr=0;rr<4;rr++){
        const int rowg = rbase + rr;
        float v = acc[i][j][rr] + bv;
        if constexpr(GELU_){ float u=v; v = 0.5f*u*(1.f+tanhf(0.7978845608028654f*(u+0.044715f*u*u*u))); }
        if constexpr(STBF) ((bf16*)Cv)[(size_t)rowg*ldc + col] = __float2bfloat16(v);
        else               ((float*)Cv)[(size_t)rowg*ldc + col] = v;
      }
    }
  }
}

// ---------------- MSDA fused prep + gather (XCD-swizzled) ----------------
__global__ __launch_bounds__(256) void msda_k(
    const bf16* __restrict__ v, const float* __restrict__ offaw,
    const float* __restrict__ refp, const int* __restrict__ sshapes,
    const int* __restrict__ lstart, bf16* __restrict__ out)
{
  __shared__ uint2 plds[8][48];
  const int bid = blockIdx.x;
  const int pid0 = ((bid & 7)*1536 + (bid >> 3))*8;
  const int tid = threadIdx.x;
  if(tid < 96){
    const int pl = tid/12, p12 = tid - pl*12;
    const int pid = pid0 + pl;
    const int bq = pid/6, h = pid - bq*6;
    const int b  = bq >> 12;
    const float* row = offaw + (size_t)bq*216;
    float mx = -1e30f;
    #pragma unroll
    for(int i=0;i<12;i++) mx = fmaxf(mx, row[144 + h*12 + i]);
    float ssum = 0.f, my = 0.f;
    #pragma unroll
    for(int i=0;i<12;i++){
      const float e = __expf(row[144 + h*12 + i] - mx);
      ssum += e;
      if(i==p12) my = e;
    }
    const float aww = my/ssum;
    const int l = p12>>2;
    const int hh = sshapes[2*l], ww = sshapes[2*l+1];
    const int st = lstart[l];
    const float rx = refp[((size_t)bq*LEVELS + l)*2 + 0];
    const float ry = refp[((size_t)bq*LEVELS + l)*2 + 1];
    const float ox = row[(h*12 + p12)*2 + 0];
    const float oy = row[(h*12 + p12)*2 + 1];
    const float px = (rx + ox/(float)ww)*(float)ww - 0.5f;
    const float py = (ry + oy/(float)hh)*(float)hh - 0.5f;
    const float fx0 = floorf(px), fy0 = floorf(py);
    const int x0 = (int)fx0, y0 = (int)fy0;
    const float wx1 = px - fx0, wx0 = 1.f - wx1;
    const float wy1 = py - fy0, wy0 = 1.f - wy1;
    #pragma unroll
    for(int c=0;c<4;c++){
      const int xi = x0 + (c&1);
      const int yi = y0 + (c>>1);
      const float wgt = (c&1 ? wx1 : wx0) * (c>>1 ? wy1 : wy0);
      const bool valid = (xi>=0) & (xi<=ww-1) & (yi>=0) & (yi<=hh-1);
      const int cx = min(max(xi,0), ww-1);
      const int cy = min(max(yi,0), hh-1);
      const unsigned off = (unsigned)((((b*NV + st + cy*ww + cx)*DIMD) + h*DH)*2);
      uint2 pr; pr.x = off; pr.y = __float_as_uint(valid ? wgt*aww : 0.f);
      plds[pl][p12*4 + c] = pr;
    }
  }
  __syncthreads();
  const int pl  = (tid>>5);
  const int pid = pid0 + pl;
  const int ch  = tid & 31;
  const char* vb = (const char*)v;
  float a0 = 0.f, a1 = 0.f;
  #pragma unroll
  for(int c=0;c<48;c++){
    const uint2 pr = plds[pl][c];
    const unsigned g = *(const unsigned*)(vb + pr.x + (ch<<2));
    const float w = __uint_as_float(pr.y);
    a0 = fmaf(w, __uint_as_float(g << 16), a0);
    a1 = fmaf(w, __uint_as_float(g & 0xffff0000u), a1);
  }
  const int bq = pid/6, h = pid - bq*6;
  const unsigned u0 = (unsigned)__builtin_bit_cast(unsigned short, __float2bfloat16(a0));
  const unsigned u1 = (unsigned)__builtin_bit_cast(unsigned short, __float2bfloat16(a1));
  *(unsigned*)((char*)out + (size_t)bq*768 + h*128 + (ch<<2)) = u0 | (u1<<16);
}

// ---------------- launcher ----------------
static inline size_t rnd(size_t x){ return (x + 511) & ~(size_t)511; }

extern "C" void kernel_launch(void* const* d_in, const int* in_sizes, int n_in,
                              void* d_out, int out_size, void* d_ws, size_t ws_size,
                              hipStream_t stream)
{
  const float* query = (const float*)d_in[0];
  const float* refp  = (const float*)d_in[1];
  const float* feat  = (const float*)d_in[2];
  const int*   sshp  = (const int*)d_in[3];
  const int*   lst   = (const int*)d_in[4];
  const float* qn_g  = (const float*)d_in[5];
  const float* qn_b  = (const float*)d_in[6];
  const float* fn_g  = (const float*)d_in[7];
  const float* fn_b  = (const float*)d_in[8];
  const float* W_off = (const float*)d_in[9];
  const float* b_off = (const float*)d_in[10];
  const float* W_aw  = (const float*)d_in[11];
  const float* b_aw  = (const float*)d_in[12];
  const float* W_v   = (const float*)d_in[13];
  const float* b_v   = (const float*)d_in[14];
  const float* W_o   = (const float*)d_in[15];
  const float* b_o   = (const float*)d_in[16];
  const float* n1_g  = (const float*)d_in[17];
  const float* n1_b  = (const float*)d_in[18];
  const float* W1    = (const float*)d_in[19];
  const float* b1    = (const float*)d_in[20];
  const float* W2    = (const float*)d_in[21];
  const float* b2    = (const float*)d_in[22];
  const float* n2_g  = (const float*)d_in[23];
  const float* n2_b  = (const float*)d_in[24];
  const float* gam   = (const float*)d_in[25];

  // ---- workspace layout ----
  char* p = (char*)d_ws;
  bf16* vbuf  = (bf16*)p;  p += rnd((size_t)MV*DIMD*2);
  bf16* qn    = (bf16*)p;  p += rnd((size_t)MQ*DIMD*2);
  bf16* wvg   = (bf16*)p;  p += rnd((size_t)147456*2);
  bf16* wo    = (bf16*)p;  p += rnd((size_t)147456*2);
  bf16* w1    = (bf16*)p;  p += rnd((size_t)393216*2);
  bf16* w2    = (bf16*)p;  p += rnd((size_t)393216*2);
  bf16* wcat  = (bf16*)p;  p += rnd((size_t)98304*2);
  float* bcat = (float*)p; p += rnd((size_t)256*4);
  float* u1   = (float*)p; p += rnd((size_t)384*4);
  float* c0   = (float*)p; p += rnd((size_t)384*4);
  bf16* hbuf  = (bf16*)p;  p += rnd((size_t)MQ*FFN*2);
  float* offaw = (float*)p; p += rnd((size_t)MQ*216*4);
  bf16*  msda  = (bf16*)p;  p += rnd((size_t)MQ*DIMD*2);
  bf16*  x2    = (bf16*)p;  p += rnd((size_t)MQ*DIMD*2);

  // 1. weights -> bf16 (g-folded Wv) + u1/c0 + LN(query)   (one launch)
  pre_k<<<NPREP + NVPREP + MQ/16, 256, 0, stream>>>(
      W_v, W_o, W1, W2, W_off, W_aw, b_off, b_aw,
      fn_g, fn_b, b_v,
      wvg, wo, w1, w2, wcat, bcat, u1, c0,
      query, qn_g, qn_b, qn);
  // 2. v = LN-fused feat @ Wvg^T  AND  offaw = qn @ Wcat^T + bcat  (one launch)
  gemm2_k<<<NVB + MQ/64, 512, 0, stream>>>(feat, wvg, u1, c0, vbuf,
                                           qn, wcat, bcat, offaw);
  // 3. fused prep+gather -> msda bf16 (XCD-swizzled)
  msda_k<<<MQ*HEADS/8, 256, 0, stream>>>(vbuf, offaw, refp, sshp, lst, msda);
  // 4. x2 = LN1(qn + msda @ W_o^T + b_o)
  gl_k<DIMD,1,32><<<MQ/32, 512, 0, stream>>>(msda, wo, b_o, qn,
                                             n1_g, n1_b, nullptr, nullptr, x2);
  // 5. h = gelu(x2 @ W1^T + b1)
  mgemm_k<1,1><<<dim3(8, MQ/128), 256, 0, stream>>>(x2, w1, b1, hbuf,
                                                    MQ, DIMD, FFN, FFN);
  // 6. out = query + gamma * LN2(x2 + h @ W2^T + b2)
  gl_k<FFN,2,32><<<MQ/32, 512, 0, stream>>>(hbuf, w2, b2, x2,
                                            n2_g, n2_b, gam, query, (float*)d_out);
}

// Round 14
// 237.594 us; speedup vs baseline: 1.1339x; 1.1339x over previous
//
#include <hip/hip_runtime.h>
#include <hip/hip_bf16.h>

// ---------------- problem constants ----------------
#define DIMD 384
#define HEADS 6
#define DH 64
#define LEVELS 3
#define POINTS 4
#define FFN 1024
#define BB 4
#define NQ 4096
#define NV 21504
#define MQ (BB*NQ)   // 16384
#define MV (BB*NV)   // 86016
#define EPSF 1e-6f

typedef __hip_bfloat16 bf16;
typedef __attribute__((ext_vector_type(8))) short bf16x8;
typedef __attribute__((ext_vector_type(4))) float f32x4;

__device__ __forceinline__ float wave_sum(float v){
  #pragma unroll
  for(int o=32;o;o>>=1) v += __shfl_xor(v,o);
  return v;
}

// ---------------- fused: LN(feat) [long pole, dispatched FIRST] + weight prep + LN(query) ----------------
// LN: 16 rows/block, 16 lanes/row, float4 loads (16B/lane) + short4 stores (8B/lane).
#define NPREP 4609
#define NLNF (MV/16)   // 5376
__global__ __launch_bounds__(256) void pre_k(
  const float* __restrict__ Wv, const float* __restrict__ Wo,
  const float* __restrict__ W1, const float* __restrict__ W2,
  const float* __restrict__ Woff, const float* __restrict__ Waw,
  const float* __restrict__ boff, const float* __restrict__ baw,
  bf16* __restrict__ wv, bf16* __restrict__ wo, bf16* __restrict__ w1,
  bf16* __restrict__ w2, bf16* __restrict__ wcat, float* __restrict__ bcat,
  const float* __restrict__ feat, const float* __restrict__ fg,
  const float* __restrict__ fb, bf16* __restrict__ featn,
  const float* __restrict__ query, const float* __restrict__ qg,
  const float* __restrict__ qb, bf16* __restrict__ qn)
{
  const int blk = blockIdx.x;
  if(blk >= NLNF && blk < NLNF + NPREP){
    int i = (blk - NLNF)*256 + threadIdx.x;
    if(i < 147456){ wv[i] = __float2bfloat16(Wv[i]); return; }
    i -= 147456;
    if(i < 147456){ wo[i] = __float2bfloat16(Wo[i]); return; }
    i -= 147456;
    if(i < 393216){ w1[i] = __float2bfloat16(W1[i]); return; }
    i -= 393216;
    if(i < 393216){ w2[i] = __float2bfloat16(W2[i]); return; }
    i -= 393216;
    if(i < 98304){
      int r = i/384, c = i - r*384;
      float v = r<144 ? Woff[r*384+c] : (r<216 ? Waw[(r-144)*384+c] : 0.f);
      wcat[i] = __float2bfloat16(v); return;
    }
    i -= 98304;
    if(i < 256){ bcat[i] = i<144 ? boff[i] : (i<216 ? baw[i-144] : 0.f); }
    return;
  }
  const float *x, *g, *b; bf16* o; int row0;
  if(blk < NLNF){ x=feat;  g=fg; b=fb; o=featn; row0 = blk*16; }
  else          { x=query; g=qg; b=qb; o=qn;    row0 = (blk - NLNF - NPREP)*16; }
  const int row = row0 + (threadIdx.x>>4);
  const int li  = threadIdx.x & 15;
  float4 va[6];
  float s=0.f, s2=0.f;
  const float* xr = x + (size_t)row*DIMD + li*4;
  #pragma unroll
  for(int j=0;j<6;j++){
    va[j] = *(const float4*)(xr + j*64);
    s  += va[j].x + va[j].y + va[j].z + va[j].w;
    s2 += va[j].x*va[j].x + va[j].y*va[j].y + va[j].z*va[j].z + va[j].w*va[j].w;
  }
  #pragma unroll
  for(int off=1; off<16; off<<=1){ s += __shfl_xor(s,off); s2 += __shfl_xor(s2,off); }
  const float m = s*(1.f/DIMD);
  const float r = rsqrtf(s2*(1.f/DIMD) - m*m + EPSF);
  #pragma unroll
  for(int j=0;j<6;j++){
    const int col = li*4 + j*64;
    const float4 g4 = *(const float4*)(g + col);
    const float4 b4 = *(const float4*)(b + col);
    short4 o4;
    o4.x = __builtin_bit_cast(short, __float2bfloat16((va[j].x-m)*r*g4.x + b4.x));
    o4.y = __builtin_bit_cast(short, __float2bfloat16((va[j].y-m)*r*g4.y + b4.y));
    o4.z = __builtin_bit_cast(short, __float2bfloat16((va[j].z-m)*r*g4.z + b4.z));
    o4.w = __builtin_bit_cast(short, __float2bfloat16((va[j].w-m)*r*g4.w + b4.w));
    *(short4*)((short*)o + (size_t)row*DIMD + col) = o4;
  }
}

// ---------------- merged GEMM: v-proj (blocks 0..1343) + offaw (blocks 1344..1599) ----------------
#define NVB (MV/64)   // 1344
__global__ __launch_bounds__(512,2) void gemm2_k(
    const bf16* __restrict__ A1, const bf16* __restrict__ B1,
    const float* __restrict__ bias1, bf16* __restrict__ out1,
    const bf16* __restrict__ A2, const bf16* __restrict__ B2,
    const float* __restrict__ bias2, float* __restrict__ out2)
{
  __shared__ __align__(16) short As[64*64];      // 8 KB
  __shared__ __align__(16) short Bs[384*64];     // 48 KB
  const int tid = threadIdx.x;
  const int wid = tid>>6, lane = tid&63;
  const int lr8 = lane>>3, lc8 = (lane&7)*8;
  const int cg = lane>>4;
  const bool vbr = blockIdx.x < NVB;

  if(vbr){
    const int m0 = blockIdx.x*64;
    f32x4 acc[4][3] = {};
    for(int k0=0; k0<DIMD; k0+=64){
      {
        const bf16* srcA = A1 + (size_t)(m0 + wid*8 + lr8)*DIMD + k0 + lc8;
        __builtin_amdgcn_global_load_lds((const __attribute__((address_space(1))) void*)srcA,
            (__attribute__((address_space(3))) void*)(As + wid*512), 16, 0, 0);
      }
      #pragma unroll
      for(int u=0;u<6;u++){
        const int t = wid*6 + u;
        const bf16* srcB = B1 + (size_t)(t*8 + lr8)*DIMD + k0 + lc8;
        __builtin_amdgcn_global_load_lds((const __attribute__((address_space(1))) void*)srcB,
            (__attribute__((address_space(3))) void*)(Bs + t*512), 16, 0, 0);
      }
      asm volatile("s_waitcnt vmcnt(0)" ::: "memory");
      __syncthreads();
      #pragma unroll
      for(int ks=0;ks<2;ks++){
        const int cbase = ks*32 + cg*8;
        bf16x8 af[4], bfr[3];
        #pragma unroll
        for(int i=0;i<4;i++)
          af[i] = *(const bf16x8*)(As + (i*16 + (lane&15))*64 + cbase);
        #pragma unroll
        for(int j=0;j<3;j++)
          bfr[j] = *(const bf16x8*)(Bs + (wid*48 + j*16 + (lane&15))*64 + cbase);
        #pragma unroll
        for(int i=0;i<4;i++)
          #pragma unroll
          for(int j=0;j<3;j++)
            acc[i][j] = __builtin_amdgcn_mfma_f32_16x16x32_bf16(af[i], bfr[j], acc[i][j], 0,0,0);
      }
      __syncthreads();
    }
    #pragma unroll
    for(int i=0;i<4;i++){
      const int r0 = m0 + i*16 + cg*4;
      #pragma unroll
      for(int j=0;j<3;j++){
        const int col = wid*48 + j*16 + (lane&15);
        const float bv = bias1[col];
        #pragma unroll
        for(int rr=0;rr<4;rr++)
          out1[(size_t)(r0+rr)*DIMD + col] = __float2bfloat16(acc[i][j][rr] + bv);
      }
    }
  } else {
    const int m0 = (blockIdx.x - NVB)*64;
    f32x4 acc[4][2] = {};
    for(int k0=0; k0<DIMD; k0+=64){
      {
        const bf16* srcA = A2 + (size_t)(m0 + wid*8 + lr8)*DIMD + k0 + lc8;
        __builtin_amdgcn_global_load_lds((const __attribute__((address_space(1))) void*)srcA,
            (__attribute__((address_space(3))) void*)(As + wid*512), 16, 0, 0);
      }
      #pragma unroll
      for(int u=0;u<4;u++){
        const int t = wid*4 + u;
        const bf16* srcB = B2 + (size_t)(t*8 + lr8)*DIMD + k0 + lc8;
        __builtin_amdgcn_global_load_lds((const __attribute__((address_space(1))) void*)srcB,
            (__attribute__((address_space(3))) void*)(Bs + t*512), 16, 0, 0);
      }
      asm volatile("s_waitcnt vmcnt(0)" ::: "memory");
      __syncthreads();
      #pragma unroll
      for(int ks=0;ks<2;ks++){
        const int cbase = ks*32 + cg*8;
        bf16x8 af[4], bfr[2];
        #pragma unroll
        for(int i=0;i<4;i++)
          af[i] = *(const bf16x8*)(As + (i*16 + (lane&15))*64 + cbase);
        #pragma unroll
        for(int j=0;j<2;j++)
          bfr[j] = *(const bf16x8*)(Bs + (wid*32 + j*16 + (lane&15))*64 + cbase);
        #pragma unroll
        for(int i=0;i<4;i++)
          #pragma unroll
          for(int j=0;j<2;j++)
            acc[i][j] = __builtin_amdgcn_mfma_f32_16x16x32_bf16(af[i], bfr[j], acc[i][j], 0,0,0);
      }
      __syncthreads();
    }
    #pragma unroll
    for(int i=0;i<4;i++){
      const int r0 = m0 + i*16 + cg*4;
      #pragma unroll
      for(int j=0;j<2;j++){
        const int col = wid*32 + j*16 + (lane&15);
        if(col >= 216) continue;
        const float bv = bias2[col];
        #pragma unroll
        for(int rr=0;rr<4;rr++)
          out2[(size_t)(r0+rr)*216 + col] = acc[i][j][rr] + bv;
      }
    }
  }
}

// ---------------- TM-row x 384-col GEMM with fused row-LN epilogue ----------------
template<int KK,int MODE,int TM>
__global__ __launch_bounds__(512,2) void gl_k(
    const bf16* __restrict__ A, const bf16* __restrict__ Bw,
    const float* __restrict__ bias, const bf16* __restrict__ res,
    const float* __restrict__ g, const float* __restrict__ b,
    const float* __restrict__ gam, const float* __restrict__ qsrc,
    void* __restrict__ out)
{
  constexpr int MI = TM/16;
  __shared__ __align__(16) short As[64*64];
  __shared__ __align__(16) short Bs[384*64];
  __shared__ float wst[8*64*2];
  __shared__ float st[64*2];
  const int tid = threadIdx.x;
  const int wid = tid>>6, lane = tid&63;
  const int m0 = blockIdx.x*TM;
  const int lr8 = lane>>3, lc8 = (lane&7)*8;
  const int cg = lane>>4;
  f32x4 acc[MI][3] = {};

  for(int k0=0; k0<KK; k0+=64){
    if(wid < TM/8){
      const bf16* srcA = A + (size_t)(m0 + wid*8 + lr8)*KK + k0 + lc8;
      __builtin_amdgcn_global_load_lds((const __attribute__((address_space(1))) void*)srcA,
          (__attribute__((address_space(3))) void*)(As + wid*512), 16, 0, 0);
    }
    #pragma unroll
    for(int u=0;u<6;u++){
      const int t = wid*6 + u;
      const bf16* srcB = Bw + (size_t)(t*8 + lr8)*KK + k0 + lc8;
      __builtin_amdgcn_global_load_lds((const __attribute__((address_space(1))) void*)srcB,
          (__attribute__((address_space(3))) void*)(Bs + t*512), 16, 0, 0);
    }
    asm volatile("s_waitcnt vmcnt(0)" ::: "memory");
    __syncthreads();
    #pragma unroll
    for(int ks=0;ks<2;ks++){
      const int cbase = ks*32 + cg*8;
      bf16x8 af[MI], bfr[3];
      #pragma unroll
      for(int i=0;i<MI;i++)
        af[i] = *(const bf16x8*)(As + (i*16 + (lane&15))*64 + cbase);
      #pragma unroll
      for(int j=0;j<3;j++)
        bfr[j] = *(const bf16x8*)(Bs + (wid*48 + j*16 + (lane&15))*64 + cbase);
      #pragma unroll
      for(int i=0;i<MI;i++)
        #pragma unroll
        for(int j=0;j<3;j++)
          acc[i][j] = __builtin_amdgcn_mfma_f32_16x16x32_bf16(af[i], bfr[j], acc[i][j], 0,0,0);
    }
    __syncthreads();
  }

  float sA[MI][4], sB[MI][4];
  #pragma unroll
  for(int i=0;i<MI;i++)
    #pragma unroll
    for(int rr=0;rr<4;rr++){ sA[i][rr]=0.f; sB[i][rr]=0.f; }
  #pragma unroll
  for(int i=0;i<MI;i++){
    #pragma unroll
    for(int j=0;j<3;j++){
      const int col = wid*48 + j*16 + (lane&15);
      const float bv = bias[col];
      #pragma unroll
      for(int rr=0;rr<4;rr++){
        const int rowg = m0 + i*16 + cg*4 + rr;
        float v = acc[i][j][rr] + bv
                + __bfloat162float(res[(size_t)rowg*DIMD + col]);
        acc[i][j][rr] = v;
        sA[i][rr] += v; sB[i][rr] += v*v;
      }
    }
  }
  #pragma unroll
  for(int off=1; off<16; off<<=1){
    #pragma unroll
    for(int i=0;i<MI;i++)
      #pragma unroll
      for(int rr=0;rr<4;rr++){
        sA[i][rr] += __shfl_xor(sA[i][rr], off);
        sB[i][rr] += __shfl_xor(sB[i][rr], off);
      }
  }
  if((lane&15)==0){
    #pragma unroll
    for(int i=0;i<MI;i++)
      #pragma unroll
      for(int rr=0;rr<4;rr++){
        const int row = i*16 + cg*4 + rr;
        wst[(wid*TM + row)*2 + 0] = sA[i][rr];
        wst[(wid*TM + row)*2 + 1] = sB[i][rr];
      }
  }
  __syncthreads();
  if(tid < TM){
    float ms=0.f, m2=0.f;
    #pragma unroll
    for(int w=0;w<8;w++){ ms += wst[(w*TM+tid)*2]; m2 += wst[(w*TM+tid)*2+1]; }
    const float m  = ms*(1.f/DIMD);
    const float rs = rsqrtf(m2*(1.f/DIMD) - m*m + EPSF);
    st[tid*2] = m; st[tid*2+1] = rs;
  }
  __syncthreads();
  #pragma unroll
  for(int i=0;i<MI;i++){
    #pragma unroll
    for(int j=0;j<3;j++){
      const int col = wid*48 + j*16 + (lane&15);
      const float gc = g[col], bc = b[col];
      #pragma unroll
      for(int rr=0;rr<4;rr++){
        const int row = i*16 + cg*4 + rr;
        const int rowg = m0 + row;
        const float t = (acc[i][j][rr] - st[row*2])*st[row*2+1]*gc + bc;
        if constexpr(MODE == 1){
          ((bf16*)out)[(size_t)rowg*DIMD + col] = __float2bfloat16(t);
        } else {
          ((float*)out)[(size_t)rowg*DIMD + col] =
              qsrc[(size_t)rowg*DIMD + col] + gam[col]*t;
        }
      }
    }
  }
}

// ---------------- bf16 MFMA GEMM (128x128 tile): C = epi(A @ W^T + bias) ----------------
template<int GELU_,int STBF>
__global__ __launch_bounds__(256) void mgemm_k(
    const bf16* __restrict__ A, const bf16* __restrict__ Bw,
    const float* __restrict__ bias, void* __restrict__ Cv,
    int M, int K, int Nreal, int ldc)
{
  __shared__ __align__(16) short As[128*64];
  __shared__ __align__(16) short Bs[128*64];
  const int tid  = threadIdx.x;
  const int wid  = tid>>6, lane = tid&63;
  const int wr   = wid>>1, wc = wid&1;
  const int m0   = blockIdx.y*128, n0 = blockIdx.x*128;
  f32x4 acc[4][4] = {};

  const int sr = (lane>>3);
  const int sc = (lane&7)*8;

  for(int k0=0; k0<K; k0+=64){
    #pragma unroll
    for(int u=0;u<4;u++){
      const int t = wid*4 + u;
      const int r = t*8 + sr;
      const bf16* srcA = A  + (size_t)(m0+r)*K + k0 + sc;
      const bf16* srcB = Bw + (size_t)(n0+r)*K + k0 + sc;
      __builtin_amdgcn_global_load_lds((const __attribute__((address_space(1))) void*)srcA,
          (__attribute__((address_space(3))) void*)(As + t*512), 16, 0, 0);
      __builtin_amdgcn_global_load_lds((const __attribute__((address_space(1))) void*)srcB,
          (__attribute__((address_space(3))) void*)(Bs + t*512), 16, 0, 0);
    }
    asm volatile("s_waitcnt vmcnt(0)" ::: "memory");
    __syncthreads();
    #pragma unroll
    for(int ks=0;ks<2;ks++){
      bf16x8 af[4], bfr[4];
      #pragma unroll
      for(int i=0;i<4;i++){
        const int ar = wr*64 + i*16 + (lane&15);
        af[i]  = *(const bf16x8*)(As + ar*64 + ks*32 + (lane>>4)*8);
        const int br = wc*64 + i*16 + (lane&15);
        bfr[i] = *(const bf16x8*)(Bs + br*64 + ks*32 + (lane>>4)*8);
      }
      #pragma unroll
      for(int i=0;i<4;i++)
        #pragma unroll
        for(int j=0;j<4;j++)
          acc[i][j] = __builtin_amdgcn_mfma_f32_16x16x32_bf16(af[i], bfr[j], acc[i][j], 0,0,0);
    }
    __syncthreads();
  }
  #pragma unroll
  for(int i=0;i<4;i++){
    const int rbase = m0 + wr*64 + i*16 + (lane>>4)*4;
    #pragma unroll
    for(int j=0;j<4;j++){
      const int col = n0 + wc*64 + j*16 + (lane&15);
      if(col >= Nreal) continue;
      const float bv = bias[col];
      #pragma unroll
      for(int rr=0;rr<4;rr++){
        const int rowg = rbase + rr;
        float v = acc[i][j][rr] + bv;
        if constexpr(GELU_){ float u=v; v = 0.5f*u*(1.f+tanhf(0.7978845608028654f*(u+0.044715f*u*u*u))); }
        if constexpr(STBF) ((bf16*)Cv)[(size_t)rowg*ldc + col] = __float2bfloat16(v);
        else               ((float*)Cv)[(size_t)rowg*ldc + col] = v;
      }
    }
  }
}

// ---------------- MSDA fused prep + gather (XCD-swizzled) ----------------
__global__ __launch_bounds__(256) void msda_k(
    const bf16* __restrict__ v, const float* __restrict__ offaw,
    const float* __restrict__ refp, const int* __restrict__ sshapes,
    const int* __restrict__ lstart, bf16* __restrict__ out)
{
  __shared__ uint2 plds[8][48];
  const int bid = blockIdx.x;
  const int pid0 = ((bid & 7)*1536 + (bid >> 3))*8;
  const int tid = threadIdx.x;
  if(tid < 96){
    const int pl = tid/12, p12 = tid - pl*12;
    const int pid = pid0 + pl;
    const int bq = pid/6, h = pid - bq*6;
    const int b  = bq >> 12;
    const float* row = offaw + (size_t)bq*216;
    float mx = -1e30f;
    #pragma unroll
    for(int i=0;i<12;i++) mx = fmaxf(mx, row[144 + h*12 + i]);
    float ssum = 0.f, my = 0.f;
    #pragma unroll
    for(int i=0;i<12;i++){
      const float e = __expf(row[144 + h*12 + i] - mx);
      ssum += e;
      if(i==p12) my = e;
    }
    const float aww = my/ssum;
    const int l = p12>>2;
    const int hh = sshapes[2*l], ww = sshapes[2*l+1];
    const int st = lstart[l];
    const float rx = refp[((size_t)bq*LEVELS + l)*2 + 0];
    const float ry = refp[((size_t)bq*LEVELS + l)*2 + 1];
    const float ox = row[(h*12 + p12)*2 + 0];
    const float oy = row[(h*12 + p12)*2 + 1];
    const float px = (rx + ox/(float)ww)*(float)ww - 0.5f;
    const float py = (ry + oy/(float)hh)*(float)hh - 0.5f;
    const float fx0 = floorf(px), fy0 = floorf(py);
    const int x0 = (int)fx0, y0 = (int)fy0;
    const float wx1 = px - fx0, wx0 = 1.f - wx1;
    const float wy1 = py - fy0, wy0 = 1.f - wy1;
    #pragma unroll
    for(int c=0;c<4;c++){
      const int xi = x0 + (c&1);
      const int yi = y0 + (c>>1);
      const float wgt = (c&1 ? wx1 : wx0) * (c>>1 ? wy1 : wy0);
      const bool valid = (xi>=0) & (xi<=ww-1) & (yi>=0) & (yi<=hh-1);
      const int cx = min(max(xi,0), ww-1);
      const int cy = min(max(yi,0), hh-1);
      const unsigned off = (unsigned)((((b*NV + st + cy*ww + cx)*DIMD) + h*DH)*2);
      uint2 pr; pr.x = off; pr.y = __float_as_uint(valid ? wgt*aww : 0.f);
      plds[pl][p12*4 + c] = pr;
    }
  }
  __syncthreads();
  const int pl  = (tid>>5);
  const int pid = pid0 + pl;
  const int ch  = tid & 31;
  const char* vb = (const char*)v;
  float a0 = 0.f, a1 = 0.f;
  #pragma unroll
  for(int c=0;c<48;c++){
    const uint2 pr = plds[pl][c];
    const unsigned g = *(const unsigned*)(vb + pr.x + (ch<<2));
    const float w = __uint_as_float(pr.y);
    a0 = fmaf(w, __uint_as_float(g << 16), a0);
    a1 = fmaf(w, __uint_as_float(g & 0xffff0000u), a1);
  }
  const int bq = pid/6, h = pid - bq*6;
  const unsigned u0 = (unsigned)__builtin_bit_cast(unsigned short, __float2bfloat16(a0));
  const unsigned u1 = (unsigned)__builtin_bit_cast(unsigned short, __float2bfloat16(a1));
  *(unsigned*)((char*)out + (size_t)bq*768 + h*128 + (ch<<2)) = u0 | (u1<<16);
}

// ---------------- launcher ----------------
static inline size_t rnd(size_t x){ return (x + 511) & ~(size_t)511; }

extern "C" void kernel_launch(void* const* d_in, const int* in_sizes, int n_in,
                              void* d_out, int out_size, void* d_ws, size_t ws_size,
                              hipStream_t stream)
{
  const float* query = (const float*)d_in[0];
  const float* refp  = (const float*)d_in[1];
  const float* feat  = (const float*)d_in[2];
  const int*   sshp  = (const int*)d_in[3];
  const int*   lst   = (const int*)d_in[4];
  const float* qn_g  = (const float*)d_in[5];
  const float* qn_b  = (const float*)d_in[6];
  const float* fn_g  = (const float*)d_in[7];
  const float* fn_b  = (const float*)d_in[8];
  const float* W_off = (const float*)d_in[9];
  const float* b_off = (const float*)d_in[10];
  const float* W_aw  = (const float*)d_in[11];
  const float* b_aw  = (const float*)d_in[12];
  const float* W_v   = (const float*)d_in[13];
  const float* b_v   = (const float*)d_in[14];
  const float* W_o   = (const float*)d_in[15];
  const float* b_o   = (const float*)d_in[16];
  const float* n1_g  = (const float*)d_in[17];
  const float* n1_b  = (const float*)d_in[18];
  const float* W1    = (const float*)d_in[19];
  const float* b1    = (const float*)d_in[20];
  const float* W2    = (const float*)d_in[21];
  const float* b2    = (const float*)d_in[22];
  const float* n2_g  = (const float*)d_in[23];
  const float* n2_b  = (const float*)d_in[24];
  const float* gam   = (const float*)d_in[25];

  // ---- workspace layout (aliased) ----
  char* p = (char*)d_ws;
  bf16* featn = (bf16*)p;                      // [MV][384] bf16, dead after gemm2
  char* late  = p;                             // aliased region, used after step 2
  p += rnd((size_t)MV*DIMD*2);
  bf16* vbuf  = (bf16*)p;  p += rnd((size_t)MV*DIMD*2);
  bf16* qn    = (bf16*)p;  p += rnd((size_t)MQ*DIMD*2);
  bf16* wv    = (bf16*)p;  p += rnd((size_t)147456*2);
  bf16* wo    = (bf16*)p;  p += rnd((size_t)147456*2);
  bf16* w1    = (bf16*)p;  p += rnd((size_t)393216*2);
  bf16* w2    = (bf16*)p;  p += rnd((size_t)393216*2);
  bf16* wcat  = (bf16*)p;  p += rnd((size_t)98304*2);
  float* bcat = (float*)p; p += rnd((size_t)256*4);
  bf16* hbuf  = (bf16*)p;  p += rnd((size_t)MQ*FFN*2);
  float* offaw = (float*)p; p += rnd((size_t)MQ*216*4);
  // late-region carve (used only after featn is dead)
  char* q2 = late;
  bf16*  msda  = (bf16*)q2;  q2 += rnd((size_t)MQ*DIMD*2);
  bf16*  x2    = (bf16*)q2;  q2 += rnd((size_t)MQ*DIMD*2);

  // 1. LN(feat) [first] + weights -> bf16 + LN(query)   (one launch)
  pre_k<<<NLNF + NPREP + MQ/16, 256, 0, stream>>>(
      W_v, W_o, W1, W2, W_off, W_aw, b_off, b_aw,
      wv, wo, w1, w2, wcat, bcat,
      feat, fn_g, fn_b, featn, query, qn_g, qn_b, qn);
  // 2. v = featn @ W_v^T + b_v  AND  offaw = qn @ Wcat^T + bcat  (one launch)
  gemm2_k<<<NVB + MQ/64, 512, 0, stream>>>(featn, wv, b_v, vbuf,
                                           qn, wcat, bcat, offaw);
  // 3. fused prep+gather -> msda bf16 (XCD-swizzled)
  msda_k<<<MQ*HEADS/8, 256, 0, stream>>>(vbuf, offaw, refp, sshp, lst, msda);
  // 4. x2 = LN1(qn + msda @ W_o^T + b_o)
  gl_k<DIMD,1,32><<<MQ/32, 512, 0, stream>>>(msda, wo, b_o, qn,
                                             n1_g, n1_b, nullptr, nullptr, x2);
  // 5. h = gelu(x2 @ W1^T + b1)
  mgemm_k<1,1><<<dim3(8, MQ/128), 256, 0, stream>>>(x2, w1, b1, hbuf,
                                                    MQ, DIMD, FFN, FFN);
  // 6. out = query + gamma * LN2(x2 + h @ W2^T + b2)
  gl_k<FFN,2,32><<<MQ/32, 512, 0, stream>>>(hbuf, w2, b2, x2,
                                            n2_g, n2_b, gam, query, (float*)d_out);
}

// Round 15
// 236.682 us; speedup vs baseline: 1.1383x; 1.0039x over previous
//
#include <hip/hip_runtime.h>
#include <hip/hip_bf16.h>

// ---------------- problem constants ----------------
#define DIMD 384
#define HEADS 6
#define DH 64
#define LEVELS 3
#define POINTS 4
#define FFN 1024
#define BB 4
#define NQ 4096
#define NV 21504
#define MQ (BB*NQ)   // 16384
#define MV (BB*NV)   // 86016
#define EPSF 1e-6f

typedef __hip_bfloat16 bf16;
typedef __attribute__((ext_vector_type(8))) short bf16x8;
typedef __attribute__((ext_vector_type(4))) float f32x4;

__device__ __forceinline__ float wave_sum(float v){
  #pragma unroll
  for(int o=32;o;o>>=1) v += __shfl_xor(v,o);
  return v;
}

__device__ __forceinline__ short4 cvt4(float4 v){
  short4 o;
  o.x = __builtin_bit_cast(short, __float2bfloat16(v.x));
  o.y = __builtin_bit_cast(short, __float2bfloat16(v.y));
  o.z = __builtin_bit_cast(short, __float2bfloat16(v.z));
  o.w = __builtin_bit_cast(short, __float2bfloat16(v.w));
  return o;
}

// ---------------- fused: LN(feat) [first] + weight prep (float4) + LN(query) ----------------
// LN: 32 rows/block, 2 rows/thread (12 float4 loads in flight), 16 lanes/row.
#define NLNF2 (MV/32)    // 2688
#define NPREP4 1153      // ceil(1179904/4/256)
__global__ __launch_bounds__(256) void pre_k(
  const float* __restrict__ Wv, const float* __restrict__ Wo,
  const float* __restrict__ W1, const float* __restrict__ W2,
  const float* __restrict__ Woff, const float* __restrict__ Waw,
  const float* __restrict__ boff, const float* __restrict__ baw,
  bf16* __restrict__ wv, bf16* __restrict__ wo, bf16* __restrict__ w1,
  bf16* __restrict__ w2, bf16* __restrict__ wcat, float* __restrict__ bcat,
  const float* __restrict__ feat, const float* __restrict__ fg,
  const float* __restrict__ fb, bf16* __restrict__ featn,
  const float* __restrict__ query, const float* __restrict__ qg,
  const float* __restrict__ qb, bf16* __restrict__ qn)
{
  const int blk = blockIdx.x;
  if(blk >= NLNF2 && blk < NLNF2 + NPREP4){
    int i = (blk - NLNF2)*1024 + threadIdx.x*4;
    if(i < 147456){
      *(short4*)((short*)wv + i) = cvt4(*(const float4*)(Wv + i)); return;
    }
    i -= 147456;
    if(i < 147456){
      *(short4*)((short*)wo + i) = cvt4(*(const float4*)(Wo + i)); return;
    }
    i -= 147456;
    if(i < 393216){
      *(short4*)((short*)w1 + i) = cvt4(*(const float4*)(W1 + i)); return;
    }
    i -= 393216;
    if(i < 393216){
      *(short4*)((short*)w2 + i) = cvt4(*(const float4*)(W2 + i)); return;
    }
    i -= 393216;
    if(i < 98304){
      const int r = i/384, c = i - r*384;
      float4 v;
      if(r < 144)      v = *(const float4*)(Woff + r*384 + c);
      else if(r < 216) v = *(const float4*)(Waw + (r-144)*384 + c);
      else             { v.x=v.y=v.z=v.w=0.f; }
      *(short4*)((short*)wcat + i) = cvt4(v); return;
    }
    i -= 98304;
    if(i < 256){
      #pragma unroll
      for(int e=0;e<4;e++){
        const int k = i + e;
        bcat[k] = k<144 ? boff[k] : (k<216 ? baw[k-144] : 0.f);
      }
    }
    return;
  }
  const float *x, *g, *b; bf16* o; int row0;
  if(blk < NLNF2){ x=feat;  g=fg; b=fb; o=featn; row0 = blk*32; }
  else           { x=query; g=qg; b=qb; o=qn;    row0 = (blk - NLNF2 - NPREP4)*32; }
  const int grp = threadIdx.x>>4;        // 0..15
  const int li  = threadIdx.x & 15;
  const int ra = row0 + grp, rb = row0 + grp + 16;
  float4 va[6], vb[6];
  float sa=0.f, s2a=0.f, sb=0.f, s2b=0.f;
  const float* xa = x + (size_t)ra*DIMD + li*4;
  const float* xb = x + (size_t)rb*DIMD + li*4;
  #pragma unroll
  for(int j=0;j<6;j++){ va[j] = *(const float4*)(xa + j*64); }
  #pragma unroll
  for(int j=0;j<6;j++){ vb[j] = *(const float4*)(xb + j*64); }
  #pragma unroll
  for(int j=0;j<6;j++){
    sa  += va[j].x + va[j].y + va[j].z + va[j].w;
    s2a += va[j].x*va[j].x + va[j].y*va[j].y + va[j].z*va[j].z + va[j].w*va[j].w;
    sb  += vb[j].x + vb[j].y + vb[j].z + vb[j].w;
    s2b += vb[j].x*vb[j].x + vb[j].y*vb[j].y + vb[j].z*vb[j].z + vb[j].w*vb[j].w;
  }
  #pragma unroll
  for(int off=1; off<16; off<<=1){
    sa += __shfl_xor(sa,off);  s2a += __shfl_xor(s2a,off);
    sb += __shfl_xor(sb,off);  s2b += __shfl_xor(s2b,off);
  }
  const float ma = sa*(1.f/DIMD);
  const float rsa = rsqrtf(s2a*(1.f/DIMD) - ma*ma + EPSF);
  const float mb = sb*(1.f/DIMD);
  const float rsb = rsqrtf(s2b*(1.f/DIMD) - mb*mb + EPSF);
  #pragma unroll
  for(int j=0;j<6;j++){
    const int col = li*4 + j*64;
    const float4 g4 = *(const float4*)(g + col);
    const float4 b4 = *(const float4*)(b + col);
    float4 ta, tb;
    ta.x=(va[j].x-ma)*rsa*g4.x+b4.x; ta.y=(va[j].y-ma)*rsa*g4.y+b4.y;
    ta.z=(va[j].z-ma)*rsa*g4.z+b4.z; ta.w=(va[j].w-ma)*rsa*g4.w+b4.w;
    tb.x=(vb[j].x-mb)*rsb*g4.x+b4.x; tb.y=(vb[j].y-mb)*rsb*g4.y+b4.y;
    tb.z=(vb[j].z-mb)*rsb*g4.z+b4.z; tb.w=(vb[j].w-mb)*rsb*g4.w+b4.w;
    *(short4*)((short*)o + (size_t)ra*DIMD + col) = cvt4(ta);
    *(short4*)((short*)o + (size_t)rb*DIMD + col) = cvt4(tb);
  }
}

// ---------------- merged GEMM: v-proj (blocks 0..1343) + offaw (blocks 1344..1599) ----------------
#define NVB (MV/64)   // 1344
__global__ __launch_bounds__(512,2) void gemm2_k(
    const bf16* __restrict__ A1, const bf16* __restrict__ B1,
    const float* __restrict__ bias1, bf16* __restrict__ out1,
    const bf16* __restrict__ A2, const bf16* __restrict__ B2,
    const float* __restrict__ bias2, float* __restrict__ out2)
{
  __shared__ __align__(16) short As[64*64];      // 8 KB
  __shared__ __align__(16) short Bs[384*64];     // 48 KB
  const int tid = threadIdx.x;
  const int wid = tid>>6, lane = tid&63;
  const int lr8 = lane>>3, lc8 = (lane&7)*8;
  const int cg = lane>>4;
  const bool vbr = blockIdx.x < NVB;

  if(vbr){
    const int m0 = blockIdx.x*64;
    f32x4 acc[4][3] = {};
    for(int k0=0; k0<DIMD; k0+=64){
      {
        const bf16* srcA = A1 + (size_t)(m0 + wid*8 + lr8)*DIMD + k0 + lc8;
        __builtin_amdgcn_global_load_lds((const __attribute__((address_space(1))) void*)srcA,
            (__attribute__((address_space(3))) void*)(As + wid*512), 16, 0, 0);
      }
      #pragma unroll
      for(int u=0;u<6;u++){
        const int t = wid*6 + u;
        const bf16* srcB = B1 + (size_t)(t*8 + lr8)*DIMD + k0 + lc8;
        __builtin_amdgcn_global_load_lds((const __attribute__((address_space(1))) void*)srcB,
            (__attribute__((address_space(3))) void*)(Bs + t*512), 16, 0, 0);
      }
      asm volatile("s_waitcnt vmcnt(0)" ::: "memory");
      __syncthreads();
      #pragma unroll
      for(int ks=0;ks<2;ks++){
        const int cbase = ks*32 + cg*8;
        bf16x8 af[4], bfr[3];
        #pragma unroll
        for(int i=0;i<4;i++)
          af[i] = *(const bf16x8*)(As + (i*16 + (lane&15))*64 + cbase);
        #pragma unroll
        for(int j=0;j<3;j++)
          bfr[j] = *(const bf16x8*)(Bs + (wid*48 + j*16 + (lane&15))*64 + cbase);
        #pragma unroll
        for(int i=0;i<4;i++)
          #pragma unroll
          for(int j=0;j<3;j++)
            acc[i][j] = __builtin_amdgcn_mfma_f32_16x16x32_bf16(af[i], bfr[j], acc[i][j], 0,0,0);
      }
      __syncthreads();
    }
    #pragma unroll
    for(int i=0;i<4;i++){
      const int r0 = m0 + i*16 + cg*4;
      #pragma unroll
      for(int j=0;j<3;j++){
        const int col = wid*48 + j*16 + (lane&15);
        const float bv = bias1[col];
        #pragma unroll
        for(int rr=0;rr<4;rr++)
          out1[(size_t)(r0+rr)*DIMD + col] = __float2bfloat16(acc[i][j][rr] + bv);
      }
    }
  } else {
    const int m0 = (blockIdx.x - NVB)*64;
    f32x4 acc[4][2] = {};
    for(int k0=0; k0<DIMD; k0+=64){
      {
        const bf16* srcA = A2 + (size_t)(m0 + wid*8 + lr8)*DIMD + k0 + lc8;
        __builtin_amdgcn_global_load_lds((const __attribute__((address_space(1))) void*)srcA,
            (__attribute__((address_space(3))) void*)(As + wid*512), 16, 0, 0);
      }
      #pragma unroll
      for(int u=0;u<4;u++){
        const int t = wid*4 + u;
        const bf16* srcB = B2 + (size_t)(t*8 + lr8)*DIMD + k0 + lc8;
        __builtin_amdgcn_global_load_lds((const __attribute__((address_space(1))) void*)srcB,
            (__attribute__((address_space(3))) void*)(Bs + t*512), 16, 0, 0);
      }
      asm volatile("s_waitcnt vmcnt(0)" ::: "memory");
      __syncthreads();
      #pragma unroll
      for(int ks=0;ks<2;ks++){
        const int cbase = ks*32 + cg*8;
        bf16x8 af[4], bfr[2];
        #pragma unroll
        for(int i=0;i<4;i++)
          af[i] = *(const bf16x8*)(As + (i*16 + (lane&15))*64 + cbase);
        #pragma unroll
        for(int j=0;j<2;j++)
          bfr[j] = *(const bf16x8*)(Bs + (wid*32 + j*16 + (lane&15))*64 + cbase);
        #pragma unroll
        for(int i=0;i<4;i++)
          #pragma unroll
          for(int j=0;j<2;j++)
            acc[i][j] = __builtin_amdgcn_mfma_f32_16x16x32_bf16(af[i], bfr[j], acc[i][j], 0,0,0);
      }
      __syncthreads();
    }
    #pragma unroll
    for(int i=0;i<4;i++){
      const int r0 = m0 + i*16 + cg*4;
      #pragma unroll
      for(int j=0;j<2;j++){
        const int col = wid*32 + j*16 + (lane&15);
        if(col >= 216) continue;
        const float bv = bias2[col];
        #pragma unroll
        for(int rr=0;rr<4;rr++)
          out2[(size_t)(r0+rr)*216 + col] = acc[i][j][rr] + bv;
      }
    }
  }
}

// ---------------- TM-row x 384-col GEMM with fused row-LN epilogue ----------------
template<int KK,int MODE,int TM>
__global__ __launch_bounds__(512,2) void gl_k(
    const bf16* __restrict__ A, const bf16* __restrict__ Bw,
    const float* __restrict__ bias, const bf16* __restrict__ res,
    const float* __restrict__ g, const float* __restrict__ b,
    const float* __restrict__ gam, const float* __restrict__ qsrc,
    void* __restrict__ out)
{
  constexpr int MI = TM/16;
  __shared__ __align__(16) short As[64*64];
  __shared__ __align__(16) short Bs[384*64];
  __shared__ float wst[8*64*2];
  __shared__ float st[64*2];
  const int tid = threadIdx.x;
  const int wid = tid>>6, lane = tid&63;
  const int m0 = blockIdx.x*TM;
  const int lr8 = lane>>3, lc8 = (lane&7)*8;
  const int cg = lane>>4;
  f32x4 acc[MI][3] = {};

  for(int k0=0; k0<KK; k0+=64){
    if(wid < TM/8){
      const bf16* srcA = A + (size_t)(m0 + wid*8 + lr8)*KK + k0 + lc8;
      __builtin_amdgcn_global_load_lds((const __attribute__((address_space(1))) void*)srcA,
          (__attribute__((address_space(3))) void*)(As + wid*512), 16, 0, 0);
    }
    #pragma unroll
    for(int u=0;u<6;u++){
      const int t = wid*6 + u;
      const bf16* srcB = Bw + (size_t)(t*8 + lr8)*KK + k0 + lc8;
      __builtin_amdgcn_global_load_lds((const __attribute__((address_space(1))) void*)srcB,
          (__attribute__((address_space(3))) void*)(Bs + t*512), 16, 0, 0);
    }
    asm volatile("s_waitcnt vmcnt(0)" ::: "memory");
    __syncthreads();
    #pragma unroll
    for(int ks=0;ks<2;ks++){
      const int cbase = ks*32 + cg*8;
      bf16x8 af[MI], bfr[3];
      #pragma unroll
      for(int i=0;i<MI;i++)
        af[i] = *(const bf16x8*)(As + (i*16 + (lane&15))*64 + cbase);
      #pragma unroll
      for(int j=0;j<3;j++)
        bfr[j] = *(const bf16x8*)(Bs + (wid*48 + j*16 + (lane&15))*64 + cbase);
      #pragma unroll
      for(int i=0;i<MI;i++)
        #pragma unroll
        for(int j=0;j<3;j++)
          acc[i][j] = __builtin_amdgcn_mfma_f32_16x16x32_bf16(af[i], bfr[j], acc[i][j], 0,0,0);
    }
    __syncthreads();
  }

  float sA[MI][4], sB[MI][4];
  #pragma unroll
  for(int i=0;i<MI;i++)
    #pragma unroll
    for(int rr=0;rr<4;rr++){ sA[i][rr]=0.f; sB[i][rr]=0.f; }
  #pragma unroll
  for(int i=0;i<MI;i++){
    #pragma unroll
    for(int j=0;j<3;j++){
      const int col = wid*48 + j*16 + (lane&15);
      const float bv = bias[col];
      #pragma unroll
      for(int rr=0;rr<4;rr++){
        const int rowg = m0 + i*16 + cg*4 + rr;
        float v = acc[i][j][rr] + bv
                + __bfloat162float(res[(size_t)rowg*DIMD + col]);
        acc[i][j][rr] = v;
        sA[i][rr] += v; sB[i][rr] += v*v;
      }
    }
  }
  #pragma unroll
  for(int off=1; off<16; off<<=1){
    #pragma unroll
    for(int i=0;i<MI;i++)
      #pragma unroll
      for(int rr=0;rr<4;rr++){
        sA[i][rr] += __shfl_xor(sA[i][rr], off);
        sB[i][rr] += __shfl_xor(sB[i][rr], off);
      }
  }
  if((lane&15)==0){
    #pragma unroll
    for(int i=0;i<MI;i++)
      #pragma unroll
      for(int rr=0;rr<4;rr++){
        const int row = i*16 + cg*4 + rr;
        wst[(wid*TM + row)*2 + 0] = sA[i][rr];
        wst[(wid*TM + row)*2 + 1] = sB[i][rr];
      }
  }
  __syncthreads();
  if(tid < TM){
    float ms=0.f, m2=0.f;
    #pragma unroll
    for(int w=0;w<8;w++){ ms += wst[(w*TM+tid)*2]; m2 += wst[(w*TM+tid)*2+1]; }
    const float m  = ms*(1.f/DIMD);
    const float rs = rsqrtf(m2*(1.f/DIMD) - m*m + EPSF);
    st[tid*2] = m; st[tid*2+1] = rs;
  }
  __syncthreads();
  #pragma unroll
  for(int i=0;i<MI;i++){
    #pragma unroll
    for(int j=0;j<3;j++){
      const int col = wid*48 + j*16 + (lane&15);
      const float gc = g[col], bc = b[col];
      #pragma unroll
      for(int rr=0;rr<4;rr++){
        const int row = i*16 + cg*4 + rr;
        const int rowg = m0 + row;
        const float t = (acc[i][j][rr] - st[row*2])*st[row*2+1]*gc + bc;
        if constexpr(MODE == 1){
          ((bf16*)out)[(size_t)rowg*DIMD + col] = __float2bfloat16(t);
        } else {
          ((float*)out)[(size_t)rowg*DIMD + col] =
              qsrc[(size_t)rowg*DIMD + col] + gam[col]*t;
        }
      }
    }
  }
}

// ---------------- bf16 MFMA GEMM (128x128 tile): C = epi(A @ W^T + bias) ----------------
template<int GELU_,int STBF>
__global__ __launch_bounds__(256) void mgemm_k(
    const bf16* __restrict__ A, const bf16* __restrict__ Bw,
    const float* __restrict__ bias, void* __restrict__ Cv,
    int M, int K, int Nreal, int ldc)
{
  __shared__ __align__(16) short As[128*64];
  __shared__ __align__(16) short Bs[128*64];
  const int tid  = threadIdx.x;
  const int wid  = tid>>6, lane = tid&63;
  const int wr   = wid>>1, wc = wid&1;
  const int m0   = blockIdx.y*128, n0 = blockIdx.x*128;
  f32x4 acc[4][4] = {};

  const int sr = (lane>>3);
  const int sc = (lane&7)*8;

  for(int k0=0; k0<K; k0+=64){
    #pragma unroll
    for(int u=0;u<4;u++){
      const int t = wid*4 + u;
      const int r = t*8 + sr;
      const bf16* srcA = A  + (size_t)(m0+r)*K + k0 + sc;
      const bf16* srcB = Bw + (size_t)(n0+r)*K + k0 + sc;
      __builtin_amdgcn_global_load_lds((const __attribute__((address_space(1))) void*)srcA,
          (__attribute__((address_space(3))) void*)(As + t*512), 16, 0, 0);
      __builtin_amdgcn_global_load_lds((const __attribute__((address_space(1))) void*)srcB,
          (__attribute__((address_space(3))) void*)(Bs + t*512), 16, 0, 0);
    }
    asm volatile("s_waitcnt vmcnt(0)" ::: "memory");
    __syncthreads();
    #pragma unroll
    for(int ks=0;ks<2;ks++){
      bf16x8 af[4], bfr[4];
      #pragma unroll
      for(int i=0;i<4;i++){
        const int ar = wr*64 + i*16 + (lane&15);
        af[i]  = *(const bf16x8*)(As + ar*64 + ks*32 + (lane>>4)*8);
        const int br = wc*64 + i*16 + (lane&15);
        bfr[i] = *(const bf16x8*)(Bs + br*64 + ks*32 + (lane>>4)*8);
      }
      #pragma unroll
      for(int i=0;i<4;i++)
        #pragma unroll
        for(int j=0;j<4;j++)
          acc[i][j] = __builtin_amdgcn_mfma_f32_16x16x32_bf16(af[i], bfr[j], acc[i][j], 0,0,0);
    }
    __syncthreads();
  }
  #pragma unroll
  for(int i=0;i<4;i++){
    const int rbase = m0 + wr*64 + i*16 + (lane>>4)*4;
    #pragma unroll
    for(int j=0;j<4;j++){
      const int col = n0 + wc*64 + j*16 + (lane&15);
      if(col >= Nreal) continue;
      const float bv = bias[col];
      #pragma unroll
      for(int rr=0;rr<4;rr++){
        const int rowg = rbase + rr;
        float v = acc[i][j][rr] + bv;
        if constexpr(GELU_){ float u=v; v = 0.5f*u*(1.f+tanhf(0.7978845608028654f*(u+0.044715f*u*u*u))); }
        if constexpr(STBF) ((bf16*)Cv)[(size_t)rowg*ldc + col] = __float2bfloat16(v);
        else               ((float*)Cv)[(size_t)rowg*ldc + col] = v;
      }
    }
  }
}

// ---------------- MSDA fused prep + gather (XCD-swizzled) ----------------
__global__ __launch_bounds__(256) void msda_k(
    const bf16* __restrict__ v, const float* __restrict__ offaw,
    const float* __restrict__ refp, const int* __restrict__ sshapes,
    const int* __restrict__ lstart, bf16* __restrict__ out)
{
  __shared__ uint2 plds[8][48];
  const int bid = blockIdx.x;
  const int pid0 = ((bid & 7)*1536 + (bid >> 3))*8;
  const int tid = threadIdx.x;
  if(tid < 96){
    const int pl = tid/12, p12 = tid - pl*12;
    const int pid = pid0 + pl;
    const int bq = pid/6, h = pid - bq*6;
    const int b  = bq >> 12;
    const float* row = offaw + (size_t)bq*216;
    float mx = -1e30f;
    #pragma unroll
    for(int i=0;i<12;i++) mx = fmaxf(mx, row[144 + h*12 + i]);
    float ssum = 0.f, my = 0.f;
    #pragma unroll
    for(int i=0;i<12;i++){
      const float e = __expf(row[144 + h*12 + i] - mx);
      ssum += e;
      if(i==p12) my = e;
    }
    const float aww = my/ssum;
    const int l = p12>>2;
    const int hh = sshapes[2*l], ww = sshapes[2*l+1];
    const int st = lstart[l];
    const float rx = refp[((size_t)bq*LEVELS + l)*2 + 0];
    const float ry = refp[((size_t)bq*LEVELS + l)*2 + 1];
    const float ox = row[(h*12 + p12)*2 + 0];
    const float oy = row[(h*12 + p12)*2 + 1];
    const float px = (rx + ox/(float)ww)*(float)ww - 0.5f;
    const float py = (ry + oy/(float)hh)*(float)hh - 0.5f;
    const float fx0 = floorf(px), fy0 = floorf(py);
    const int x0 = (int)fx0, y0 = (int)fy0;
    const float wx1 = px - fx0, wx0 = 1.f - wx1;
    const float wy1 = py - fy0, wy0 = 1.f - wy1;
    #pragma unroll
    for(int c=0;c<4;c++){
      const int xi = x0 + (c&1);
      const int yi = y0 + (c>>1);
      const float wgt = (c&1 ? wx1 : wx0) * (c>>1 ? wy1 : wy0);
      const bool valid = (xi>=0) & (xi<=ww-1) & (yi>=0) & (yi<=hh-1);
      const int cx = min(max(xi,0), ww-1);
      const int cy = min(max(yi,0), hh-1);
      const unsigned off = (unsigned)((((b*NV + st + cy*ww + cx)*DIMD) + h*DH)*2);
      uint2 pr; pr.x = off; pr.y = __float_as_uint(valid ? wgt*aww : 0.f);
      plds[pl][p12*4 + c] = pr;
    }
  }
  __syncthreads();
  const int pl  = (tid>>5);
  const int pid = pid0 + pl;
  const int ch  = tid & 31;
  const char* vb = (const char*)v;
  float a0 = 0.f, a1 = 0.f;
  #pragma unroll
  for(int c=0;c<48;c++){
    const uint2 pr = plds[pl][c];
    const unsigned g = *(const unsigned*)(vb + pr.x + (ch<<2));
    const float w = __uint_as_float(pr.y);
    a0 = fmaf(w, __uint_as_float(g << 16), a0);
    a1 = fmaf(w, __uint_as_float(g & 0xffff0000u), a1);
  }
  const int bq = pid/6, h = pid - bq*6;
  const unsigned u0 = (unsigned)__builtin_bit_cast(unsigned short, __float2bfloat16(a0));
  const unsigned u1 = (unsigned)__builtin_bit_cast(unsigned short, __float2bfloat16(a1));
  *(unsigned*)((char*)out + (size_t)bq*768 + h*128 + (ch<<2)) = u0 | (u1<<16);
}

// ---------------- launcher ----------------
static inline size_t rnd(size_t x){ return (x + 511) & ~(size_t)511; }

extern "C" void kernel_launch(void* const* d_in, const int* in_sizes, int n_in,
                              void* d_out, int out_size, void* d_ws, size_t ws_size,
                              hipStream_t stream)
{
  const float* query = (const float*)d_in[0];
  const float* refp  = (const float*)d_in[1];
  const float* feat  = (const float*)d_in[2];
  const int*   sshp  = (const int*)d_in[3];
  const int*   lst   = (const int*)d_in[4];
  const float* qn_g  = (const float*)d_in[5];
  const float* qn_b  = (const float*)d_in[6];
  const float* fn_g  = (const float*)d_in[7];
  const float* fn_b  = (const float*)d_in[8];
  const float* W_off = (const float*)d_in[9];
  const float* b_off = (const float*)d_in[10];
  const float* W_aw  = (const float*)d_in[11];
  const float* b_aw  = (const float*)d_in[12];
  const float* W_v   = (const float*)d_in[13];
  const float* b_v   = (const float*)d_in[14];
  const float* W_o   = (const float*)d_in[15];
  const float* b_o   = (const float*)d_in[16];
  const float* n1_g  = (const float*)d_in[17];
  const float* n1_b  = (const float*)d_in[18];
  const float* W1    = (const float*)d_in[19];
  const float* b1    = (const float*)d_in[20];
  const float* W2    = (const float*)d_in[21];
  const float* b2    = (const float*)d_in[22];
  const float* n2_g  = (const float*)d_in[23];
  const float* n2_b  = (const float*)d_in[24];
  const float* gam   = (const float*)d_in[25];

  // ---- workspace layout (aliased) ----
  char* p = (char*)d_ws;
  bf16* featn = (bf16*)p;                      // [MV][384] bf16, dead after gemm2
  char* late  = p;                             // aliased region, used after step 2
  p += rnd((size_t)MV*DIMD*2);
  bf16* vbuf  = (bf16*)p;  p += rnd((size_t)MV*DIMD*2);
  bf16* qn    = (bf16*)p;  p += rnd((size_t)MQ*DIMD*2);
  bf16* wv    = (bf16*)p;  p += rnd((size_t)147456*2);
  bf16* wo    = (bf16*)p;  p += rnd((size_t)147456*2);
  bf16* w1    = (bf16*)p;  p += rnd((size_t)393216*2);
  bf16* w2    = (bf16*)p;  p += rnd((size_t)393216*2);
  bf16* wcat  = (bf16*)p;  p += rnd((size_t)98304*2);
  float* bcat = (float*)p; p += rnd((size_t)256*4);
  bf16* hbuf  = (bf16*)p;  p += rnd((size_t)MQ*FFN*2);
  float* offaw = (float*)p; p += rnd((size_t)MQ*216*4);
  // late-region carve (used only after featn is dead)
  char* q2 = late;
  bf16*  msda  = (bf16*)q2;  q2 += rnd((size_t)MQ*DIMD*2);
  bf16*  x2    = (bf16*)q2;  q2 += rnd((size_t)MQ*DIMD*2);

  // 1. LN(feat) [first, 2 rows/thread] + weights (float4) + LN(query)
  pre_k<<<NLNF2 + NPREP4 + MQ/32, 256, 0, stream>>>(
      W_v, W_o, W1, W2, W_off, W_aw, b_off, b_aw,
      wv, wo, w1, w2, wcat, bcat,
      feat, fn_g, fn_b, featn, query, qn_g, qn_b, qn);
  // 2. v = featn @ W_v^T + b_v  AND  offaw = qn @ Wcat^T + bcat  (one launch)
  gemm2_k<<<NVB + MQ/64, 512, 0, stream>>>(featn, wv, b_v, vbuf,
                                           qn, wcat, bcat, offaw);
  // 3. fused prep+gather -> msda bf16 (XCD-swizzled)
  msda_k<<<MQ*HEADS/8, 256, 0, stream>>>(vbuf, offaw, refp, sshp, lst, msda);
  // 4. x2 = LN1(qn + msda @ W_o^T + b_o)
  gl_k<DIMD,1,32><<<MQ/32, 512, 0, stream>>>(msda, wo, b_o, qn,
                                             n1_g, n1_b, nullptr, nullptr, x2);
  // 5. h = gelu(x2 @ W1^T + b1)
  mgemm_k<1,1><<<dim3(8, MQ/128), 256, 0, stream>>>(x2, w1, b1, hbuf,
                                                    MQ, DIMD, FFN, FFN);
  // 6. out = query + gamma * LN2(x2 + h @ W2^T + b2)
  gl_k<FFN,2,32><<<MQ/32, 512, 0, stream>>>(hbuf, w2, b2, x2,
                                            n2_g, n2_b, gam, query, (float*)d_out);
}